// Round 19
// baseline (2836.874 us; speedup 1.0000x reference)
//
#include <hip/hip_runtime.h>

// ---- sizes (fixed by the problem) ----
#define Bsz 64
#define Tsz 64
#define Vsz 32000
#define DEsz 512
#define DDsz 1024
#define DCsz 512
#define DIN 1024     // DE+DC
#define G3 3072      // 3*DD

typedef unsigned short u16;
typedef unsigned int   u32;
typedef unsigned long long u64;
typedef __attribute__((ext_vector_type(8))) __bf16 bf16x8;
typedef __attribute__((ext_vector_type(4))) float f32x4;

__device__ __forceinline__ u16 f2bf(float f) {
    union { float f; unsigned int u; } v; v.f = f;
    unsigned int r = v.u + 0x7fffu + ((v.u >> 16) & 1u);  // RNE
    return (u16)(r >> 16);
}

__device__ __forceinline__ void gload_lds16(const u16* g, u16* l) {
    __builtin_amdgcn_global_load_lds(
        (const __attribute__((address_space(1))) void*)g,
        (__attribute__((address_space(3))) void*)l, 16, 0, 0);
}

__device__ __forceinline__ float fast_sigmoid(float x) {
    float xc = fminf(fmaxf(x, -30.f), 30.f);
    return 1.f / (1.f + __expf(-xc));
}
__device__ __forceinline__ float fast_tanh(float x) {
    float xc = fminf(fmaxf(x, -15.f), 15.f);
    float e = __expf(2.f * xc);
    return (e - 1.f) / (e + 1.f);
}

// ---------- f32 -> bf16 bulk convert ----------
__global__ void f32_to_bf16(const float* __restrict__ src, u16* __restrict__ dst, long n) {
    long i = ((long)blockIdx.x * blockDim.x + threadIdx.x) * 4;
    if (i + 3 < n) {
        float4 v = *(const float4*)&src[i];
        dst[i + 0] = f2bf(v.x);
        dst[i + 1] = f2bf(v.y);
        dst[i + 2] = f2bf(v.z);
        dst[i + 3] = f2bf(v.w);
    }
}

// ---------- build X = concat(emb[token], context) bf16, row = b*T + t ----------
__global__ void build_x(const float* __restrict__ emb, const float* __restrict__ ctx,
                        const int* __restrict__ labels, const int* __restrict__ bos,
                        u16* __restrict__ X) {
    int i = blockIdx.x;            // 0..4095 = b*64 + t
    int b = i >> 6;
    int t = i & 63;
    int tok = (t == 0) ? *bos : labels[b * Tsz + (t - 1)];
    const float* s0 = emb + (long)tok * DEsz;
    const float* s1 = ctx + (long)b * DCsz;
    u16* dst = X + (long)i * DIN;
    for (int c = threadIdx.x; c < DEsz; c += blockDim.x) {
        dst[c]        = f2bf(s0[c]);
        dst[DEsz + c] = f2bf(s1[c]);
    }
}

// ---------- 128x128 GEMM (gi): LDS-staged FULL-LINE stores ----------
__global__ __launch_bounds__(256) void gemm128(
    const u16* __restrict__ A, const u16* __restrict__ Bm,
    const float* __restrict__ bias, float* __restrict__ C,
    int N, int K, int mblk)
{
    __shared__ __align__(16) u16 As[128 * 32];
    __shared__ __align__(16) u16 Bs[128 * 32];
    __shared__ __align__(16) float stage[32 * 132];
    const int tid  = threadIdx.x;
    const int wave = tid >> 6;
    const int lane = tid & 63;
    const int wm = wave >> 1, wn = wave & 1;

    int nwg = gridDim.x;
    int wg  = blockIdx.x;
    int cpx = nwg >> 3;
    wg = (wg & 7) * cpx + (wg >> 3);
    const int bm = (wg % mblk) * 128;
    const int bn = (wg / mblk) * 128;

    const int sr = tid >> 2;
    const int sc = (tid & 3) * 8;
    const u16* ga0 = A  + (long)(bm + sr) * K + sc;
    const u16* ga1 = A  + (long)(bm + 64 + sr) * K + sc;
    const u16* gb0 = Bm + (long)(bn + sr) * K + sc;
    const u16* gb1 = Bm + (long)(bn + 64 + sr) * K + sc;
    u16* la0 = As + tid * 8;
    u16* la1 = As + 2048 + tid * 8;
    u16* lb0 = Bs + tid * 8;
    u16* lb1 = Bs + 2048 + tid * 8;

    const int fr = lane & 15;
    const int kh = (lane >> 4) * 8;

    f32x4 acc[4][4];
    #pragma unroll
    for (int i = 0; i < 4; ++i)
        #pragma unroll
        for (int j = 0; j < 4; ++j) acc[i][j] = f32x4{0.f, 0.f, 0.f, 0.f};

    for (int k0 = 0; k0 < K; k0 += 32) {
        gload_lds16(ga0 + k0, la0);
        gload_lds16(ga1 + k0, la1);
        gload_lds16(gb0 + k0, lb0);
        gload_lds16(gb1 + k0, lb1);
        __syncthreads();
        bf16x8 af[4], bf[4];
        #pragma unroll
        for (int mi = 0; mi < 4; ++mi)
            af[mi] = *(const bf16x8*)&As[(wm * 64 + mi * 16 + fr) * 32 + kh];
        #pragma unroll
        for (int ni = 0; ni < 4; ++ni)
            bf[ni] = *(const bf16x8*)&Bs[(wn * 64 + ni * 16 + fr) * 32 + kh];
        #pragma unroll
        for (int mi = 0; mi < 4; ++mi)
            #pragma unroll
            for (int ni = 0; ni < 4; ++ni)
                acc[mi][ni] = __builtin_amdgcn_mfma_f32_16x16x32_bf16(af[mi], bf[ni], acc[mi][ni], 0, 0, 0);
        __syncthreads();
    }

    const int r0 = (lane >> 4) * 4;
    float bv[4];
    #pragma unroll
    for (int ni = 0; ni < 4; ++ni) bv[ni] = bias[bn + wn * 64 + ni * 16 + fr];

    #pragma unroll
    for (int mi = 0; mi < 4; ++mi) {
        __syncthreads();
        #pragma unroll
        for (int ni = 0; ni < 4; ++ni) {
            int scol = wn * 64 + ni * 16 + fr;
            #pragma unroll
            for (int j = 0; j < 4; ++j)
                stage[(wm * 16 + r0 + j) * 132 + scol] = acc[mi][ni][j] + bv[ni];
        }
        __syncthreads();
        #pragma unroll
        for (int p = 0; p < 4; ++p) {
            int idx  = p * 256 + tid;
            int srow = idx >> 5;
            int sc4  = (idx & 31) * 4;
            f32x4 v = *(const f32x4*)&stage[srow * 132 + sc4];
            int grow = bm + mi * 16 + (srow & 15) + (srow >> 4) * 64;
            __builtin_nontemporal_store(v, (f32x4*)&C[(long)grow * N + bn + sc4]);
        }
    }
}

// ---------- logits GEMM: A staged DIRECTLY from k-major hT; out[b][t][v] ----------
__global__ __launch_bounds__(256) void gemm_hT(
    const u16* __restrict__ hT, const u16* __restrict__ Bm,
    const float* __restrict__ bias, float* __restrict__ C,
    int N, int mblk)
{
    __shared__ __align__(16) u16 As[128 * 32];
    __shared__ __align__(16) u16 Bs[128 * 32];
    __shared__ __align__(16) float stage[32 * 132];
    const int tid  = threadIdx.x;
    const int wave = tid >> 6;
    const int lane = tid & 63;
    const int wm = wave >> 1, wn = wave & 1;

    int nwg = gridDim.x;
    int wg  = blockIdx.x;
    int cpx = nwg >> 3;
    wg = (wg & 7) * cpx + (wg >> 3);
    const int bm = (wg % mblk) * 128;
    const int bn = (wg / mblk) * 128;

    const int sr = tid >> 2;
    const int sc = (tid & 3) * 8;
    const int rA0 = bm + sr, rA1 = bm + 64 + sr;
    const u16* ga0 = hT + (long)(rA0 >> 6) * 65536 + (rA0 & 63) * 32 + sc;
    const u16* ga1 = hT + (long)(rA1 >> 6) * 65536 + (rA1 & 63) * 32 + sc;
    const u16* gb0 = Bm + (long)(bn + sr) * DDsz + sc;
    const u16* gb1 = Bm + (long)(bn + 64 + sr) * DDsz + sc;
    u16* la0 = As + tid * 8;
    u16* la1 = As + 2048 + tid * 8;
    u16* lb0 = Bs + tid * 8;
    u16* lb1 = Bs + 2048 + tid * 8;

    const int fr = lane & 15;
    const int kh = (lane >> 4) * 8;

    f32x4 acc[4][4];
    #pragma unroll
    for (int i = 0; i < 4; ++i)
        #pragma unroll
        for (int j = 0; j < 4; ++j) acc[i][j] = f32x4{0.f, 0.f, 0.f, 0.f};

    for (int k0 = 0; k0 < DDsz; k0 += 32) {
        gload_lds16(ga0 + k0 * 64, la0);     // hT: k0-stride = 2048 u16
        gload_lds16(ga1 + k0 * 64, la1);
        gload_lds16(gb0 + k0, lb0);
        gload_lds16(gb1 + k0, lb1);
        __syncthreads();
        bf16x8 af[4], bf[4];
        #pragma unroll
        for (int mi = 0; mi < 4; ++mi)
            af[mi] = *(const bf16x8*)&As[(wm * 64 + mi * 16 + fr) * 32 + kh];
        #pragma unroll
        for (int ni = 0; ni < 4; ++ni)
            bf[ni] = *(const bf16x8*)&Bs[(wn * 64 + ni * 16 + fr) * 32 + kh];
        #pragma unroll
        for (int mi = 0; mi < 4; ++mi)
            #pragma unroll
            for (int ni = 0; ni < 4; ++ni)
                acc[mi][ni] = __builtin_amdgcn_mfma_f32_16x16x32_bf16(af[mi], bf[ni], acc[mi][ni], 0, 0, 0);
        __syncthreads();
    }

    const int r0 = (lane >> 4) * 4;
    float bv[4];
    #pragma unroll
    for (int ni = 0; ni < 4; ++ni) bv[ni] = bias[bn + wn * 64 + ni * 16 + fr];

    #pragma unroll
    for (int mi = 0; mi < 4; ++mi) {
        __syncthreads();
        #pragma unroll
        for (int ni = 0; ni < 4; ++ni) {
            int scol = wn * 64 + ni * 16 + fr;
            #pragma unroll
            for (int j = 0; j < 4; ++j)
                stage[(wm * 16 + r0 + j) * 132 + scol] = acc[mi][ni][j] + bv[ni];
        }
        __syncthreads();
        #pragma unroll
        for (int p = 0; p < 4; ++p) {
            int idx  = p * 256 + tid;
            int srow = idx >> 5;
            int sc4  = (idx & 31) * 4;
            f32x4 v = *(const f32x4*)&stage[srow * 132 + sc4];
            int r    = bm + mi * 16 + (srow & 15) + (srow >> 4) * 64;  // t*64+b
            int orow = ((r & 63) << 6) | (r >> 6);                     // b*64+t
            __builtin_nontemporal_store(v, (f32x4*)&C[(long)orow * N + bn + sc4]);
        }
    }
}

// ---------- persistent GRU v11 (r17 / 878us best): dual-chain per-wave barrier ----------
#define PF 8
__global__ __launch_bounds__(256) void gru_persist(
    const u16* __restrict__ Whh, const float* __restrict__ bhh,
    const float* __restrict__ gi, const float* __restrict__ initp,
    u16* __restrict__ hT, int* __restrict__ arr, int* __restrict__ rel)
{
    __builtin_amdgcn_fence(__ATOMIC_ACQUIRE, "agent");

    __shared__ __align__(16) u16 Wl[48 * 1032];
    __shared__ __align__(16) u16 h0l[1024];
    const int tid  = threadIdx.x;
    const int w    = tid >> 6;
    const int lane = tid & 63;
    const int c0   = blockIdx.x * 16;
    const int fr   = lane & 15;
    const int kh   = (lane >> 4) * 8;
    const int r0   = (lane >> 4) * 4;
    const int kb_s = blockIdx.x >> 1;
    const int kio  = (blockIdx.x & 1) * 16;
    const int chain  = w >> 1;
    const int myline = ((chain << 3) | (blockIdx.x & 7)) << 4;

    for (int ch = tid; ch < 48 * 128; ch += 256) {
        int r  = ch >> 7;
        int cc = (ch & 127) * 8;
        int g  = r >> 4, i = r & 15;
        *(bf16x8*)&Wl[r * 1032 + cc] =
            *(const bf16x8*)&Whh[((long)g * DDsz + c0 + i) * DDsz + cc];
    }
    #pragma unroll
    for (int i = 0; i < 4; ++i) h0l[tid * 4 + i] = f2bf(initp[tid * 4 + i]);
    __syncthreads();

    float hc[4];
    { float v = initp[c0 + fr];
      #pragma unroll
      for (int j = 0; j < 4; ++j) hc[j] = v; }
    const float bR = bhh[c0 + fr];
    const float bZ = bhh[DDsz + c0 + fr];
    const float bN = bhh[2 * DDsz + c0 + fr];

    float gir[4], giz[4], gin_[4];
    #pragma unroll
    for (int j = 0; j < 4; ++j) {
        long gib = ((long)(w * 16 + r0 + j) * Tsz) * G3 + c0 + fr;
        gir[j]  = gi[gib];
        giz[j]  = gi[gib + DDsz];
        gin_[j] = gi[gib + 2 * DDsz];
    }

    for (int t = 0; t < Tsz; ++t) {
        f32x4 acc[3];
        #pragma unroll
        for (int g = 0; g < 3; ++g) acc[g] = f32x4{0.f, 0.f, 0.f, 0.f};

        auto mfma3 = [&](bf16x8 a, int k) {
            bf16x8 wr_ = *(const bf16x8*)&Wl[(0  + fr) * 1032 + k * 32 + kh];
            bf16x8 wz_ = *(const bf16x8*)&Wl[(16 + fr) * 1032 + k * 32 + kh];
            bf16x8 wn_ = *(const bf16x8*)&Wl[(32 + fr) * 1032 + k * 32 + kh];
            acc[0] = __builtin_amdgcn_mfma_f32_16x16x32_bf16(a, wr_, acc[0], 0, 0, 0);
            acc[1] = __builtin_amdgcn_mfma_f32_16x16x32_bf16(a, wz_, acc[1], 0, 0, 0);
            acc[2] = __builtin_amdgcn_mfma_f32_16x16x32_bf16(a, wn_, acc[2], 0, 0, 0);
        };

        if (t == 0) {
            #pragma unroll
            for (int k = 0; k < 32; ++k) mfma3(*(const bf16x8*)&h0l[k * 32 + kh], k);
        } else {
            const u16* q0 = hT + ((long)(t - 1) * 32 * 64 + w * 16) * 32 + fr * 32 + kh;
            bf16x8 p0[PF];
            #pragma unroll
            for (int p = 0; p < PF; ++p) p0[p] = *(const bf16x8*)(q0 + p * 2048);
            #pragma unroll
            for (int k = 0; k < 32; ++k) {
                bf16x8 a = p0[k & (PF - 1)];
                if (k < 32 - PF) p0[k & (PF - 1)] = *(const bf16x8*)(q0 + (k + PF) * 2048);
                mfma3(a, k);
            }
        }

        #pragma unroll
        for (int j = 0; j < 4; ++j) {
            int b = w * 16 + r0 + j;
            float r = fast_sigmoid(gir[j] + acc[0][j] + bR);
            float z = fast_sigmoid(giz[j] + acc[1][j] + bZ);
            float n = fast_tanh(gin_[j] + r * (acc[2][j] + bN));
            float h = (1.f - z) * n + z * hc[j];
            hc[j] = h;
            int hb = (int)f2bf(h);
            int pb = __shfl_xor(hb, 1, 64);
            if (!(fr & 1)) {
                u32 val = ((u32)pb << 16) | (u32)hb;
                __hip_atomic_store(
                    (u32*)(hT + (((long)t * 32 + kb_s) * 64 + b) * 32 + kio + fr), val,
                    __ATOMIC_RELAXED, __HIP_MEMORY_SCOPE_AGENT);
            }
        }

        if (t != Tsz - 1) {
            asm volatile("" ::: "memory");
            int tp = t + 1;
            #pragma unroll
            for (int j = 0; j < 4; ++j) {
                long gib = ((long)(w * 16 + r0 + j) * Tsz + tp) * G3 + c0 + fr;
                gir[j]  = gi[gib];
                giz[j]  = gi[gib + DDsz];
                gin_[j] = gi[gib + 2 * DDsz];
            }
            asm volatile("s_waitcnt vmcnt(12)" ::: "memory");
            if (lane == 0) {
                __hip_atomic_fetch_add(&arr[myline], 1,
                                       __ATOMIC_RELAXED, __HIP_MEMORY_SCOPE_AGENT);
                if (blockIdx.x == 0 && (w & 1) == 0) {
                    const int tgt = 128 * (t + 1);
                    for (;;) {
                        int s = 0;
                        #pragma unroll
                        for (int g = 0; g < 8; ++g)
                            s += __hip_atomic_load(&arr[((chain << 3) | g) << 4],
                                                   __ATOMIC_RELAXED,
                                                   __HIP_MEMORY_SCOPE_AGENT);
                        if (s >= tgt) break;
                    }
                    __hip_atomic_store(&rel[chain << 4], t + 1,
                                       __ATOMIC_RELAXED, __HIP_MEMORY_SCOPE_AGENT);
                } else {
                    while (__hip_atomic_load(&rel[chain << 4], __ATOMIC_RELAXED,
                                             __HIP_MEMORY_SCOPE_AGENT) < t + 1) { }
                }
            }
            asm volatile("" ::: "memory");
        }
    }
}

// ============================================================================
// PROBE: same structure, MODE ablations.
// 0=faithful copy  1=no MFMA/W-LDS  2=no h-global-load  3=no gi load  4=no store
template<int MODE>
__global__ __launch_bounds__(256) void gru_probe(
    const u16* __restrict__ Whh, const float* __restrict__ bhh,
    const float* __restrict__ gi, const float* __restrict__ initp,
    u16* __restrict__ hT, int* __restrict__ arr, int* __restrict__ rel)
{
    __builtin_amdgcn_fence(__ATOMIC_ACQUIRE, "agent");

    __shared__ __align__(16) u16 Wl[48 * 1032];
    __shared__ __align__(16) u16 h0l[1024];
    const int tid  = threadIdx.x;
    const int w    = tid >> 6;
    const int lane = tid & 63;
    const int c0   = blockIdx.x * 16;
    const int fr   = lane & 15;
    const int kh   = (lane >> 4) * 8;
    const int r0   = (lane >> 4) * 4;
    const int kb_s = blockIdx.x >> 1;
    const int kio  = (blockIdx.x & 1) * 16;
    const int chain  = w >> 1;
    const int myline = ((chain << 3) | (blockIdx.x & 7)) << 4;

    for (int ch = tid; ch < 48 * 128; ch += 256) {
        int r  = ch >> 7;
        int cc = (ch & 127) * 8;
        int g  = r >> 4, i = r & 15;
        *(bf16x8*)&Wl[r * 1032 + cc] =
            *(const bf16x8*)&Whh[((long)g * DDsz + c0 + i) * DDsz + cc];
    }
    #pragma unroll
    for (int i = 0; i < 4; ++i) h0l[tid * 4 + i] = f2bf(initp[tid * 4 + i]);
    __syncthreads();

    float hc[4];
    { float v = initp[c0 + fr];
      #pragma unroll
      for (int j = 0; j < 4; ++j) hc[j] = v; }
    const float bR = bhh[c0 + fr];
    const float bZ = bhh[DDsz + c0 + fr];
    const float bN = bhh[2 * DDsz + c0 + fr];

    float gir[4], giz[4], gin_[4];
    #pragma unroll
    for (int j = 0; j < 4; ++j) {
        if (MODE == 3) { gir[j] = 0.f; giz[j] = 0.f; gin_[j] = 0.f; }
        else {
            long gib = ((long)(w * 16 + r0 + j) * Tsz) * G3 + c0 + fr;
            gir[j]  = gi[gib];
            giz[j]  = gi[gib + DDsz];
            gin_[j] = gi[gib + 2 * DDsz];
        }
    }

    u32 dead = 0;
    for (int t = 0; t < Tsz; ++t) {
        f32x4 acc[3];
        #pragma unroll
        for (int g = 0; g < 3; ++g) acc[g] = f32x4{0.f, 0.f, 0.f, 0.f};

        auto mfma3 = [&](bf16x8 a, int k) {
            bf16x8 wr_ = *(const bf16x8*)&Wl[(0  + fr) * 1032 + k * 32 + kh];
            bf16x8 wz_ = *(const bf16x8*)&Wl[(16 + fr) * 1032 + k * 32 + kh];
            bf16x8 wn_ = *(const bf16x8*)&Wl[(32 + fr) * 1032 + k * 32 + kh];
            acc[0] = __builtin_amdgcn_mfma_f32_16x16x32_bf16(a, wr_, acc[0], 0, 0, 0);
            acc[1] = __builtin_amdgcn_mfma_f32_16x16x32_bf16(a, wz_, acc[1], 0, 0, 0);
            acc[2] = __builtin_amdgcn_mfma_f32_16x16x32_bf16(a, wn_, acc[2], 0, 0, 0);
        };
        auto sink = [&](bf16x8 a) {
            union { bf16x8 v; u32 u[4]; } cv; cv.v = a;
            dead ^= cv.u[0] ^ cv.u[1] ^ cv.u[2] ^ cv.u[3];
        };

        if (t == 0 || MODE == 2) {
            #pragma unroll
            for (int k = 0; k < 32; ++k) {
                bf16x8 a = *(const bf16x8*)&h0l[k * 32 + kh];
                if (MODE == 1) sink(a); else mfma3(a, k);
            }
        } else {
            const u16* q0 = hT + ((long)(t - 1) * 32 * 64 + w * 16) * 32 + fr * 32 + kh;
            bf16x8 p0[PF];
            #pragma unroll
            for (int p = 0; p < PF; ++p) p0[p] = *(const bf16x8*)(q0 + p * 2048);
            #pragma unroll
            for (int k = 0; k < 32; ++k) {
                bf16x8 a = p0[k & (PF - 1)];
                if (k < 32 - PF) p0[k & (PF - 1)] = *(const bf16x8*)(q0 + (k + PF) * 2048);
                if (MODE == 1) sink(a); else mfma3(a, k);
            }
        }

        #pragma unroll
        for (int j = 0; j < 4; ++j) {
            int b = w * 16 + r0 + j;
            float r = fast_sigmoid(gir[j] + acc[0][j] + bR);
            float z = fast_sigmoid(giz[j] + acc[1][j] + bZ);
            float n = fast_tanh(gin_[j] + r * (acc[2][j] + bN));
            float h = (1.f - z) * n + z * hc[j];
            hc[j] = h;
            int hb = (int)f2bf(h);
            int pb = __shfl_xor(hb, 1, 64);
            u32 val = ((u32)pb << 16) | (u32)hb;
            if (MODE == 4) {
                dead ^= val;
            } else if (!(fr & 1)) {
                __hip_atomic_store(
                    (u32*)(hT + (((long)t * 32 + kb_s) * 64 + b) * 32 + kio + fr), val,
                    __ATOMIC_RELAXED, __HIP_MEMORY_SCOPE_AGENT);
            }
        }

        if (t != Tsz - 1) {
            asm volatile("" ::: "memory");
            if (MODE != 3) {
                int tp = t + 1;
                #pragma unroll
                for (int j = 0; j < 4; ++j) {
                    long gib = ((long)(w * 16 + r0 + j) * Tsz + tp) * G3 + c0 + fr;
                    gir[j]  = gi[gib];
                    giz[j]  = gi[gib + DDsz];
                    gin_[j] = gi[gib + 2 * DDsz];
                }
                asm volatile("s_waitcnt vmcnt(12)" ::: "memory");
            } else {
                asm volatile("s_waitcnt vmcnt(0)" ::: "memory");
            }
            if (lane == 0) {
                __hip_atomic_fetch_add(&arr[myline], 1,
                                       __ATOMIC_RELAXED, __HIP_MEMORY_SCOPE_AGENT);
                if (blockIdx.x == 0 && (w & 1) == 0) {
                    const int tgt = 128 * (t + 1);
                    for (;;) {
                        int s = 0;
                        #pragma unroll
                        for (int g = 0; g < 8; ++g)
                            s += __hip_atomic_load(&arr[((chain << 3) | g) << 4],
                                                   __ATOMIC_RELAXED,
                                                   __HIP_MEMORY_SCOPE_AGENT);
                        if (s >= tgt) break;
                    }
                    __hip_atomic_store(&rel[chain << 4], t + 1,
                                       __ATOMIC_RELAXED, __HIP_MEMORY_SCOPE_AGENT);
                } else {
                    while (__hip_atomic_load(&rel[chain << 4], __ATOMIC_RELAXED,
                                             __HIP_MEMORY_SCOPE_AGENT) < t + 1) { }
                }
            }
            asm volatile("" ::: "memory");
        }
    }
    if (dead == 0xDEADBEEFu)                    // never true; keeps `dead` live
        ((volatile u32*)hT)[tid] = dead;
}

extern "C" void kernel_launch(void* const* d_in, const int* in_sizes, int n_in,
                              void* d_out, int out_size, void* d_ws, size_t ws_size,
                              hipStream_t stream) {
    const float* ctx    = (const float*)d_in[0];
    const int*   labels = (const int*)  d_in[1];
    const float* emb    = (const float*)d_in[2];
    const float* W_ih   = (const float*)d_in[3];
    const float* b_ih   = (const float*)d_in[4];
    const float* W_hh   = (const float*)d_in[5];
    const float* b_hh   = (const float*)d_in[6];
    const float* initp  = (const float*)d_in[7];
    const float* W_out  = (const float*)d_in[8];
    const float* b_out  = (const float*)d_in[9];
    const int*   bos    = (const int*)  d_in[10];
    float* out = (float*)d_out;

    char* ws = (char*)d_ws;
    u16*   Xbf    = (u16*)  (ws + 0L);            //  8,388,608
    float* gi     = (float*)(ws + 8388608L);      // 50,331,648
    u16*   hT     = (u16*)  (ws + 67108864L);     //  8,388,608  (k-major)
    u16*   Wih_b  = (u16*)  (ws + 75497472L);     //  6,291,456
    u16*   Whh_b  = (u16*)  (ws + 81788928L);     //  6,291,456
    u16*   Wout_b = (u16*)  (ws + 88080384L);     // 65,536,000 -> 153,616,384
    int*   arr    = (int*)  (ws + 153616384L);    // 1 KB
    int*   rel    = (int*)  (ws + 153617408L);    // 128 B
    char*  pctr   = ws + 153618432L;              // 5 x 2 KB probe counters
    u16*   hT2    = (u16*)  (ws + 153628672L);    // 8,388,608 probe scratch

    (void)hipMemsetAsync(arr, 0, 2048, stream);
    (void)hipMemsetAsync(pctr, 0, 10240, stream);

    long n1 = (long)G3 * DIN;
    long n2 = (long)Vsz * DDsz;
    f32_to_bf16<<<(unsigned)(n1 / 4 / 256), 256, 0, stream>>>(W_ih, Wih_b, n1);
    f32_to_bf16<<<(unsigned)(n1 / 4 / 256), 256, 0, stream>>>(W_hh, Whh_b, n1);
    f32_to_bf16<<<(unsigned)(n2 / 4 / 256), 256, 0, stream>>>(W_out, Wout_b, n2);

    build_x<<<Bsz * Tsz, 128, 0, stream>>>(emb, ctx, labels, bos, Xbf);

    gemm128<<<(4096 / 128) * (G3 / 128), 256, 0, stream>>>(
        Xbf, Wih_b, b_ih, gi, G3, DIN, 4096 / 128);

    gru_persist<<<DDsz / 16, 256, 0, stream>>>(Whh_b, b_hh, gi, initp, hT, arr, rel);

    gemm_hT<<<(4096 / 128) * (Vsz / 128), 256, 0, stream>>>(
        hT, Wout_b, b_out, out, Vsz, 4096 / 128);

    // ---- diagnostic probes (after real pipeline; outputs unused) ----
    gru_probe<0><<<64, 256, 0, stream>>>(Whh_b, b_hh, gi, initp, hT2,
                                         (int*)(pctr + 0 * 2048), (int*)(pctr + 0 * 2048 + 1024));
    gru_probe<1><<<64, 256, 0, stream>>>(Whh_b, b_hh, gi, initp, hT2,
                                         (int*)(pctr + 1 * 2048), (int*)(pctr + 1 * 2048 + 1024));
    gru_probe<2><<<64, 256, 0, stream>>>(Whh_b, b_hh, gi, initp, hT2,
                                         (int*)(pctr + 2 * 2048), (int*)(pctr + 2 * 2048 + 1024));
    gru_probe<3><<<64, 256, 0, stream>>>(Whh_b, b_hh, gi, initp, hT2,
                                         (int*)(pctr + 3 * 2048), (int*)(pctr + 3 * 2048 + 1024));
    gru_probe<4><<<64, 256, 0, stream>>>(Whh_b, b_hh, gi, initp, hT2,
                                         (int*)(pctr + 4 * 2048), (int*)(pctr + 4 * 2048 + 1024));
}

// Round 20
// 774.481 us; speedup vs baseline: 3.6629x; 3.6629x over previous
//
#include <hip/hip_runtime.h>

// ---- sizes (fixed by the problem) ----
#define Bsz 64
#define Tsz 64
#define Vsz 32000
#define DEsz 512
#define DDsz 1024
#define DCsz 512
#define DIN 1024     // DE+DC
#define G3 3072      // 3*DD

typedef unsigned short u16;
typedef unsigned int   u32;
typedef unsigned long long u64;
typedef __attribute__((ext_vector_type(8))) __bf16 bf16x8;
typedef __attribute__((ext_vector_type(4))) float f32x4;

__device__ __forceinline__ u16 f2bf(float f) {
    union { float f; unsigned int u; } v; v.f = f;
    unsigned int r = v.u + 0x7fffu + ((v.u >> 16) & 1u);  // RNE
    return (u16)(r >> 16);
}

__device__ __forceinline__ void gload_lds16(const u16* g, u16* l) {
    __builtin_amdgcn_global_load_lds(
        (const __attribute__((address_space(1))) void*)g,
        (__attribute__((address_space(3))) void*)l, 16, 0, 0);
}

__device__ __forceinline__ void wait_vmcnt(int n) {
    switch (n) {
    case 0: asm volatile("s_waitcnt vmcnt(0)" ::: "memory"); break;
    case 1: asm volatile("s_waitcnt vmcnt(1)" ::: "memory"); break;
    case 2: asm volatile("s_waitcnt vmcnt(2)" ::: "memory"); break;
    case 3: asm volatile("s_waitcnt vmcnt(3)" ::: "memory"); break;
    case 4: asm volatile("s_waitcnt vmcnt(4)" ::: "memory"); break;
    case 5: asm volatile("s_waitcnt vmcnt(5)" ::: "memory"); break;
    case 6: asm volatile("s_waitcnt vmcnt(6)" ::: "memory"); break;
    default: asm volatile("s_waitcnt vmcnt(7)" ::: "memory"); break;
    }
}

__device__ __forceinline__ float fast_sigmoid(float x) {
    float xc = fminf(fmaxf(x, -30.f), 30.f);
    return 1.f / (1.f + __expf(-xc));
}
__device__ __forceinline__ float fast_tanh(float x) {
    float xc = fminf(fmaxf(x, -15.f), 15.f);
    float e = __expf(2.f * xc);
    return (e - 1.f) / (e + 1.f);
}

// ---------- f32 -> bf16 bulk convert ----------
__global__ void f32_to_bf16(const float* __restrict__ src, u16* __restrict__ dst, long n) {
    long i = ((long)blockIdx.x * blockDim.x + threadIdx.x) * 4;
    if (i + 3 < n) {
        float4 v = *(const float4*)&src[i];
        dst[i + 0] = f2bf(v.x);
        dst[i + 1] = f2bf(v.y);
        dst[i + 2] = f2bf(v.z);
        dst[i + 3] = f2bf(v.w);
    }
}

// ---------- build X = concat(emb[token], context) bf16, row = b*T + t ----------
__global__ void build_x(const float* __restrict__ emb, const float* __restrict__ ctx,
                        const int* __restrict__ labels, const int* __restrict__ bos,
                        u16* __restrict__ X) {
    int i = blockIdx.x;            // 0..4095 = b*64 + t
    int b = i >> 6;
    int t = i & 63;
    int tok = (t == 0) ? *bos : labels[b * Tsz + (t - 1)];
    const float* s0 = emb + (long)tok * DEsz;
    const float* s1 = ctx + (long)b * DCsz;
    u16* dst = X + (long)i * DIN;
    for (int c = threadIdx.x; c < DEsz; c += blockDim.x) {
        dst[c]        = f2bf(s0[c]);
        dst[DEsz + c] = f2bf(s1[c]);
    }
}

// ---------- 128x128 GEMM (gi): LDS-staged FULL-LINE stores ----------
__global__ __launch_bounds__(256) void gemm128(
    const u16* __restrict__ A, const u16* __restrict__ Bm,
    const float* __restrict__ bias, float* __restrict__ C,
    int N, int K, int mblk)
{
    __shared__ __align__(16) u16 As[128 * 32];
    __shared__ __align__(16) u16 Bs[128 * 32];
    __shared__ __align__(16) float stage[32 * 132];
    const int tid  = threadIdx.x;
    const int wave = tid >> 6;
    const int lane = tid & 63;
    const int wm = wave >> 1, wn = wave & 1;

    int nwg = gridDim.x;
    int wg  = blockIdx.x;
    int cpx = nwg >> 3;
    wg = (wg & 7) * cpx + (wg >> 3);
    const int bm = (wg % mblk) * 128;
    const int bn = (wg / mblk) * 128;

    const int sr = tid >> 2;
    const int sc = (tid & 3) * 8;
    const u16* ga0 = A  + (long)(bm + sr) * K + sc;
    const u16* ga1 = A  + (long)(bm + 64 + sr) * K + sc;
    const u16* gb0 = Bm + (long)(bn + sr) * K + sc;
    const u16* gb1 = Bm + (long)(bn + 64 + sr) * K + sc;
    u16* la0 = As + tid * 8;
    u16* la1 = As + 2048 + tid * 8;
    u16* lb0 = Bs + tid * 8;
    u16* lb1 = Bs + 2048 + tid * 8;

    const int fr = lane & 15;
    const int kh = (lane >> 4) * 8;

    f32x4 acc[4][4];
    #pragma unroll
    for (int i = 0; i < 4; ++i)
        #pragma unroll
        for (int j = 0; j < 4; ++j) acc[i][j] = f32x4{0.f, 0.f, 0.f, 0.f};

    for (int k0 = 0; k0 < K; k0 += 32) {
        gload_lds16(ga0 + k0, la0);
        gload_lds16(ga1 + k0, la1);
        gload_lds16(gb0 + k0, lb0);
        gload_lds16(gb1 + k0, lb1);
        __syncthreads();
        bf16x8 af[4], bf[4];
        #pragma unroll
        for (int mi = 0; mi < 4; ++mi)
            af[mi] = *(const bf16x8*)&As[(wm * 64 + mi * 16 + fr) * 32 + kh];
        #pragma unroll
        for (int ni = 0; ni < 4; ++ni)
            bf[ni] = *(const bf16x8*)&Bs[(wn * 64 + ni * 16 + fr) * 32 + kh];
        #pragma unroll
        for (int mi = 0; mi < 4; ++mi)
            #pragma unroll
            for (int ni = 0; ni < 4; ++ni)
                acc[mi][ni] = __builtin_amdgcn_mfma_f32_16x16x32_bf16(af[mi], bf[ni], acc[mi][ni], 0, 0, 0);
        __syncthreads();
    }

    const int r0 = (lane >> 4) * 4;
    float bv[4];
    #pragma unroll
    for (int ni = 0; ni < 4; ++ni) bv[ni] = bias[bn + wn * 64 + ni * 16 + fr];

    #pragma unroll
    for (int mi = 0; mi < 4; ++mi) {
        __syncthreads();
        #pragma unroll
        for (int ni = 0; ni < 4; ++ni) {
            int scol = wn * 64 + ni * 16 + fr;
            #pragma unroll
            for (int j = 0; j < 4; ++j)
                stage[(wm * 16 + r0 + j) * 132 + scol] = acc[mi][ni][j] + bv[ni];
        }
        __syncthreads();
        #pragma unroll
        for (int p = 0; p < 4; ++p) {
            int idx  = p * 256 + tid;
            int srow = idx >> 5;
            int sc4  = (idx & 31) * 4;
            f32x4 v = *(const f32x4*)&stage[srow * 132 + sc4];
            int grow = bm + mi * 16 + (srow & 15) + (srow >> 4) * 64;
            __builtin_nontemporal_store(v, (f32x4*)&C[(long)grow * N + bn + sc4]);
        }
    }
}

// ---------- logits GEMM: A staged DIRECTLY from k-major hT; out[b][t][v] ----------
__global__ __launch_bounds__(256) void gemm_hT(
    const u16* __restrict__ hT, const u16* __restrict__ Bm,
    const float* __restrict__ bias, float* __restrict__ C,
    int N, int mblk)
{
    __shared__ __align__(16) u16 As[128 * 32];
    __shared__ __align__(16) u16 Bs[128 * 32];
    __shared__ __align__(16) float stage[32 * 132];
    const int tid  = threadIdx.x;
    const int wave = tid >> 6;
    const int lane = tid & 63;
    const int wm = wave >> 1, wn = wave & 1;

    int nwg = gridDim.x;
    int wg  = blockIdx.x;
    int cpx = nwg >> 3;
    wg = (wg & 7) * cpx + (wg >> 3);
    const int bm = (wg % mblk) * 128;
    const int bn = (wg / mblk) * 128;

    const int sr = tid >> 2;
    const int sc = (tid & 3) * 8;
    const int rA0 = bm + sr, rA1 = bm + 64 + sr;
    const u16* ga0 = hT + (long)(rA0 >> 6) * 65536 + (rA0 & 63) * 32 + sc;
    const u16* ga1 = hT + (long)(rA1 >> 6) * 65536 + (rA1 & 63) * 32 + sc;
    const u16* gb0 = Bm + (long)(bn + sr) * DDsz + sc;
    const u16* gb1 = Bm + (long)(bn + 64 + sr) * DDsz + sc;
    u16* la0 = As + tid * 8;
    u16* la1 = As + 2048 + tid * 8;
    u16* lb0 = Bs + tid * 8;
    u16* lb1 = Bs + 2048 + tid * 8;

    const int fr = lane & 15;
    const int kh = (lane >> 4) * 8;

    f32x4 acc[4][4];
    #pragma unroll
    for (int i = 0; i < 4; ++i)
        #pragma unroll
        for (int j = 0; j < 4; ++j) acc[i][j] = f32x4{0.f, 0.f, 0.f, 0.f};

    for (int k0 = 0; k0 < DDsz; k0 += 32) {
        gload_lds16(ga0 + k0 * 64, la0);     // hT: k0-stride = 2048 u16
        gload_lds16(ga1 + k0 * 64, la1);
        gload_lds16(gb0 + k0, lb0);
        gload_lds16(gb1 + k0, lb1);
        __syncthreads();
        bf16x8 af[4], bf[4];
        #pragma unroll
        for (int mi = 0; mi < 4; ++mi)
            af[mi] = *(const bf16x8*)&As[(wm * 64 + mi * 16 + fr) * 32 + kh];
        #pragma unroll
        for (int ni = 0; ni < 4; ++ni)
            bf[ni] = *(const bf16x8*)&Bs[(wn * 64 + ni * 16 + fr) * 32 + kh];
        #pragma unroll
        for (int mi = 0; mi < 4; ++mi)
            #pragma unroll
            for (int ni = 0; ni < 4; ++ni)
                acc[mi][ni] = __builtin_amdgcn_mfma_f32_16x16x32_bf16(af[mi], bf[ni], acc[mi][ni], 0, 0, 0);
        __syncthreads();
    }

    const int r0 = (lane >> 4) * 4;
    float bv[4];
    #pragma unroll
    for (int ni = 0; ni < 4; ++ni) bv[ni] = bias[bn + wn * 64 + ni * 16 + fr];

    #pragma unroll
    for (int mi = 0; mi < 4; ++mi) {
        __syncthreads();
        #pragma unroll
        for (int ni = 0; ni < 4; ++ni) {
            int scol = wn * 64 + ni * 16 + fr;
            #pragma unroll
            for (int j = 0; j < 4; ++j)
                stage[(wm * 16 + r0 + j) * 132 + scol] = acc[mi][ni][j] + bv[ni];
        }
        __syncthreads();
        #pragma unroll
        for (int p = 0; p < 4; ++p) {
            int idx  = p * 256 + tid;
            int srow = idx >> 5;
            int sc4  = (idx & 31) * 4;
            f32x4 v = *(const f32x4*)&stage[srow * 132 + sc4];
            int r    = bm + mi * 16 + (srow & 15) + (srow >> 4) * 64;  // t*64+b
            int orow = ((r & 63) << 6) | (r >> 6);                     // b*64+t
            __builtin_nontemporal_store(v, (f32x4*)&C[(long)orow * N + bn + sc4]);
        }
    }
}

// ---------- persistent GRU v13: ASYNC h staging (global_load_lds ring-8) ----------
// 64 blocks x 256 thr; dual-chain per-wave barrier (r17). Per wave, k-fragment
// = 1024B contiguous -> ONE gload_lds16 per k-step into an 8-slot LDS ring;
// counted vmcnt keeps 7 loads in flight. Source pre-swizzled + matching
// XOR on ds_read: 2-way (free) bank access instead of 8-way.
__global__ __launch_bounds__(256) void gru_persist(
    const u16* __restrict__ Whh, const float* __restrict__ bhh,
    const float* __restrict__ gi, const float* __restrict__ initp,
    u16* __restrict__ hT, int* __restrict__ arr, int* __restrict__ rel)
{
    __builtin_amdgcn_fence(__ATOMIC_ACQUIRE, "agent");

    __shared__ __align__(16) u16 Wl[48 * 1032];    //  99,072 B
    __shared__ __align__(16) u16 h0l[1024];        //   2,048 B
    __shared__ __align__(16) u16 hstg[4 * 4096];   //  32,768 B (4 waves x 8 slots x 512)
    const int tid  = threadIdx.x;
    const int w    = tid >> 6;
    const int lane = tid & 63;
    const int c0   = blockIdx.x * 16;
    const int fr   = lane & 15;
    const int kh   = (lane >> 4) * 8;
    const int r0   = (lane >> 4) * 4;
    const int kb_s = blockIdx.x >> 1;
    const int kio  = (blockIdx.x & 1) * 16;
    const int chain  = w >> 1;
    const int myline = ((chain << 3) | (blockIdx.x & 7)) << 4;

    // staging addresses
    // global per-lane (pre-swizzled): fragment byte = l*16 ^ ((l>>3)&3)<<4
    const int gswz_u16 = ((lane * 16) ^ (((lane >> 3) & 3) << 4)) >> 1;
    // ds_read per-lane byte offset within slot (same XOR)
    const int rdoff = (fr * 64 + (lane >> 4) * 16) ^ (((fr >> 1) & 3) << 4);
    u16* const stg = &hstg[w * 4096];              // wave-uniform slot base
    const char* const stgc = (const char*)stg;

    for (int ch = tid; ch < 48 * 128; ch += 256) {
        int r  = ch >> 7;
        int cc = (ch & 127) * 8;
        int g  = r >> 4, i = r & 15;
        *(bf16x8*)&Wl[r * 1032 + cc] =
            *(const bf16x8*)&Whh[((long)g * DDsz + c0 + i) * DDsz + cc];
    }
    #pragma unroll
    for (int i = 0; i < 4; ++i) h0l[tid * 4 + i] = f2bf(initp[tid * 4 + i]);
    __syncthreads();

    float hc[4];
    { float v = initp[c0 + fr];
      #pragma unroll
      for (int j = 0; j < 4; ++j) hc[j] = v; }
    const float bR = bhh[c0 + fr];
    const float bZ = bhh[DDsz + c0 + fr];
    const float bN = bhh[2 * DDsz + c0 + fr];

    float gir[4], giz[4], gin_[4];
    #pragma unroll
    for (int j = 0; j < 4; ++j) {
        long gib = ((long)(w * 16 + r0 + j) * Tsz) * G3 + c0 + fr;
        gir[j]  = gi[gib];
        giz[j]  = gi[gib + DDsz];
        gin_[j] = gi[gib + 2 * DDsz];
    }

    for (int t = 0; t < Tsz; ++t) {
        f32x4 acc[3];
        #pragma unroll
        for (int g = 0; g < 3; ++g) acc[g] = f32x4{0.f, 0.f, 0.f, 0.f};

        auto mfma3 = [&](bf16x8 a, int k) {
            bf16x8 wr_ = *(const bf16x8*)&Wl[(0  + fr) * 1032 + k * 32 + kh];
            bf16x8 wz_ = *(const bf16x8*)&Wl[(16 + fr) * 1032 + k * 32 + kh];
            bf16x8 wn_ = *(const bf16x8*)&Wl[(32 + fr) * 1032 + k * 32 + kh];
            acc[0] = __builtin_amdgcn_mfma_f32_16x16x32_bf16(a, wr_, acc[0], 0, 0, 0);
            acc[1] = __builtin_amdgcn_mfma_f32_16x16x32_bf16(a, wz_, acc[1], 0, 0, 0);
            acc[2] = __builtin_amdgcn_mfma_f32_16x16x32_bf16(a, wn_, acc[2], 0, 0, 0);
        };

        if (t == 0) {
            #pragma unroll
            for (int k = 0; k < 32; ++k) mfma3(*(const bf16x8*)&h0l[k * 32 + kh], k);
        } else {
            // async-staged h: fragment k base (u16) = (t-1)*65536 + k*2048 + w*512
            const u16* fb = hT + (long)(t - 1) * 65536 + w * 512 + gswz_u16;
            #pragma unroll
            for (int s = 0; s < 8; ++s)
                gload_lds16(fb + s * 2048, stg + s * 512);
            #pragma unroll
            for (int k = 0; k < 32; ++k) {
                wait_vmcnt(k < 24 ? 7 : 31 - k);     // h-load k landed
                bf16x8 a = *(const bf16x8*)(stgc + (k & 7) * 1024 + rdoff);
                mfma3(a, k);
                if (k < 24)
                    gload_lds16(fb + (k + 8) * 2048, stg + (k & 7) * 512);
            }
        }

        #pragma unroll
        for (int j = 0; j < 4; ++j) {
            int b = w * 16 + r0 + j;
            float r = fast_sigmoid(gir[j] + acc[0][j] + bR);
            float z = fast_sigmoid(giz[j] + acc[1][j] + bZ);
            float n = fast_tanh(gin_[j] + r * (acc[2][j] + bN));
            float h = (1.f - z) * n + z * hc[j];
            hc[j] = h;
            int hb = (int)f2bf(h);
            int pb = __shfl_xor(hb, 1, 64);
            if (!(fr & 1)) {
                u32 val = ((u32)pb << 16) | (u32)hb;
                __hip_atomic_store(
                    (u32*)(hT + (((long)t * 32 + kb_s) * 64 + b) * 32 + kio + fr), val,
                    __ATOMIC_RELAXED, __HIP_MEMORY_SCOPE_AGENT);
            }
        }

        if (t != Tsz - 1) {
            asm volatile("" ::: "memory");
            int tp = t + 1;
            #pragma unroll
            for (int j = 0; j < 4; ++j) {
                long gib = ((long)(w * 16 + r0 + j) * Tsz + tp) * G3 + c0 + fr;
                gir[j]  = gi[gib];
                giz[j]  = gi[gib + DDsz];
                gin_[j] = gi[gib + 2 * DDsz];
            }
            asm volatile("s_waitcnt vmcnt(12)" ::: "memory");   // stores drained
            if (lane == 0) {
                __hip_atomic_fetch_add(&arr[myline], 1,
                                       __ATOMIC_RELAXED, __HIP_MEMORY_SCOPE_AGENT);
                if (blockIdx.x == 0 && (w & 1) == 0) {
                    const int tgt = 128 * (t + 1);
                    for (;;) {
                        int s = 0;
                        #pragma unroll
                        for (int g = 0; g < 8; ++g)
                            s += __hip_atomic_load(&arr[((chain << 3) | g) << 4],
                                                   __ATOMIC_RELAXED,
                                                   __HIP_MEMORY_SCOPE_AGENT);
                        if (s >= tgt) break;
                    }
                    __hip_atomic_store(&rel[chain << 4], t + 1,
                                       __ATOMIC_RELAXED, __HIP_MEMORY_SCOPE_AGENT);
                } else {
                    while (__hip_atomic_load(&rel[chain << 4], __ATOMIC_RELAXED,
                                             __HIP_MEMORY_SCOPE_AGENT) < t + 1) { }
                }
            }
            asm volatile("" ::: "memory");
        }
    }
}

extern "C" void kernel_launch(void* const* d_in, const int* in_sizes, int n_in,
                              void* d_out, int out_size, void* d_ws, size_t ws_size,
                              hipStream_t stream) {
    const float* ctx    = (const float*)d_in[0];
    const int*   labels = (const int*)  d_in[1];
    const float* emb    = (const float*)d_in[2];
    const float* W_ih   = (const float*)d_in[3];
    const float* b_ih   = (const float*)d_in[4];
    const float* W_hh   = (const float*)d_in[5];
    const float* b_hh   = (const float*)d_in[6];
    const float* initp  = (const float*)d_in[7];
    const float* W_out  = (const float*)d_in[8];
    const float* b_out  = (const float*)d_in[9];
    const int*   bos    = (const int*)  d_in[10];
    float* out = (float*)d_out;

    char* ws = (char*)d_ws;
    u16*   Xbf    = (u16*)  (ws + 0L);            //  8,388,608
    float* gi     = (float*)(ws + 8388608L);      // 50,331,648
    u16*   hT     = (u16*)  (ws + 67108864L);     //  8,388,608  (k-major)
    u16*   Wih_b  = (u16*)  (ws + 75497472L);     //  6,291,456
    u16*   Whh_b  = (u16*)  (ws + 81788928L);     //  6,291,456
    u16*   Wout_b = (u16*)  (ws + 88080384L);     // 65,536,000 -> 153,616,384
    int*   arr    = (int*)  (ws + 153616384L);    // 1 KB
    int*   rel    = (int*)  (ws + 153617408L);    // 128 B

    (void)hipMemsetAsync(arr, 0, 2048, stream);

    long n1 = (long)G3 * DIN;
    long n2 = (long)Vsz * DDsz;
    f32_to_bf16<<<(unsigned)(n1 / 4 / 256), 256, 0, stream>>>(W_ih, Wih_b, n1);
    f32_to_bf16<<<(unsigned)(n1 / 4 / 256), 256, 0, stream>>>(W_hh, Whh_b, n1);
    f32_to_bf16<<<(unsigned)(n2 / 4 / 256), 256, 0, stream>>>(W_out, Wout_b, n2);

    build_x<<<Bsz * Tsz, 128, 0, stream>>>(emb, ctx, labels, bos, Xbf);

    gemm128<<<(4096 / 128) * (G3 / 128), 256, 0, stream>>>(
        Xbf, Wih_b, b_ih, gi, G3, DIN, 4096 / 128);

    gru_persist<<<DDsz / 16, 256, 0, stream>>>(Whh_b, b_hh, gi, initp, hT, arr, rel);

    gemm_hT<<<(4096 / 128) * (Vsz / 128), 256, 0, stream>>>(
        hT, Wout_b, b_out, out, Vsz, 4096 / 128);
}